// Round 9
// baseline (213.936 us; speedup 1.0000x reference)
//
#include <hip/hip_runtime.h>
#include <math.h>

#define TTOK 8192
#define DIM  2048
#define NH   1024

// ---- workspace layout (float offsets) ----
#define OFF_PART6 0u          // [256][16][2048] = 8388608
#define OFF_NUM   8388608u    // [8192][16]
#define OFF_COMB  8519680u    // [8192][16]
#define OFF_CSUM  8650752u    // [256][16]
#define OFF_MUSUM 8654848u    // [256][16]
#define OFF_ENT   8658944u    // [256]
#define OFF_SRAW  8659200u    // [16][2048]
#define OFF_HBUF  8691968u    // [16][1024]
#define OFF_SLOT  8708352u    // [16][2048] -> end 8741120 floats = 35.0 MB

// ---- d_out layout (float offsets) ----
#define O_OUT   0u
#define O_LOSS  16777216u
#define O_GATE  16777217u
#define O_TOPI  16908289u
#define O_TOPW  16924673u
#define O_MU    16941057u
#define O_ENTR  16941073u
#define O_DISP  16941074u

// KAD: fused logits + row-softmax outputs + slot_in partials.
// grid 256 blocks (32 tokens each) x 512 threads.
// P1: 2-token x 16-expert register-blocked logit dots (thread = token-pair x 64-f chunk)
// P2: softmax outputs from LDS. P3: part6 accumulation (x re-read, cache-warm).
__global__ __launch_bounds__(512) void kad(const float* __restrict__ x,
    const float* __restrict__ Wd,
    float* __restrict__ num, float* __restrict__ comb, float* __restrict__ gate_out,
    float* __restrict__ topi_out, float* __restrict__ topw_out,
    float* __restrict__ csum_p, float* __restrict__ musum_p, float* __restrict__ ent_p,
    float* __restrict__ part6){
  const int blk = blockIdx.x;
  const int tid = threadIdx.x;
  const int t0  = blk*32;
  __shared__ float sS[32][17];                   // logits, padded (P2 row reads)
  __shared__ __align__(16) float sN[32][16];     // exp(logits), float4-broadcast in P3
  __shared__ float sC[32][16];                   // combine rows
  __shared__ float sE[32];

  // ---- P1: logits ----
  {
    const int ttp = tid>>5;                      // 0..15 -> tokens 2ttp, 2ttp+1
    const int kc  = tid&31;                      // 64-float chunk of D
    const float4* xr0 = (const float4*)(x + (size_t)(t0+2*ttp  )*DIM + kc*64);
    const float4* xr1 = (const float4*)(x + (size_t)(t0+2*ttp+1)*DIM + kc*64);
    float a0[16], a1[16];
    #pragma unroll
    for (int e=0;e<16;e++){ a0[e]=0.f; a1[e]=0.f; }
    #pragma unroll
    for (int k4=0;k4<16;k4++){
      float4 x0 = xr0[k4];
      float4 x1 = xr1[k4];
      #pragma unroll
      for (int e=0;e<16;e++){
        float4 w = *(const float4*)(Wd + e*DIM + kc*64 + k4*4);
        a0[e] += x0.x*w.x + x0.y*w.y + x0.z*w.z + x0.w*w.w;
        a1[e] += x1.x*w.x + x1.y*w.y + x1.z*w.z + x1.w*w.w;
      }
    }
    // reduce over the 32 kc-lanes (xor <=16 stays inside each 32-group)
    #pragma unroll
    for (int o=1;o<32;o<<=1){
      #pragma unroll
      for (int e=0;e<16;e++){
        a0[e] += __shfl_xor(a0[e],o,64);
        a1[e] += __shfl_xor(a1[e],o,64);
      }
    }
    if (kc==0){
      #pragma unroll
      for (int e=0;e<16;e++){
        sS[2*ttp  ][e] = a0[e];  sN[2*ttp  ][e] = expf(a0[e]);  // |logit|<~6: no shift needed
        sS[2*ttp+1][e] = a1[e];  sN[2*ttp+1][e] = expf(a1[e]);
      }
    }
  }
  __syncthreads();
  // num -> global (KE' dispatch needs it)
  if (tid<128) ((float4*)num)[(size_t)blk*128 + tid] = ((const float4*)sN)[tid];
  // ---- P2: per-token softmax outputs ----
  if (tid<32){
    const int gt = t0 + tid;
    float l[16];
    #pragma unroll
    for (int e=0;e<16;e++) l[e] = sS[tid][e];
    float m = l[0];
    #pragma unroll
    for (int e=1;e<16;e++) m = fmaxf(m,l[e]);
    float c[16]; float sm=0.f;
    #pragma unroll
    for (int e=0;e<16;e++){ c[e]=expf(l[e]-m); sm+=c[e]; }
    float inv = 1.f/sm;
    #pragma unroll
    for (int e=0;e<16;e++) c[e]*=inv;
    float4* co = (float4*)(comb + (size_t)gt*16);
    co[0]=make_float4(c[0],c[1],c[2],c[3]);   co[1]=make_float4(c[4],c[5],c[6],c[7]);
    co[2]=make_float4(c[8],c[9],c[10],c[11]); co[3]=make_float4(c[12],c[13],c[14],c[15]);
    float* go = gate_out + (size_t)gt*16;      // 4B-aligned region -> scalar
    #pragma unroll
    for (int e=0;e<16;e++) go[e]=c[e];
    float v0=-1.f,v1=-1.f; int i0=0,i1=0;
    #pragma unroll
    for (int e=0;e<16;e++){
      float ce=c[e];
      if (ce>v0){ v1=v0;i1=i0; v0=ce;i0=e; }
      else if (ce>v1){ v1=ce;i1=e; }
    }
    float dn = fmaxf(v0+v1,1e-8f);
    topi_out[(size_t)gt*2+0]=(float)i0; topi_out[(size_t)gt*2+1]=(float)i1;
    topw_out[(size_t)gt*2+0]=v0/dn;     topw_out[(size_t)gt*2+1]=v1/dn;
    float ent=0.f;
    #pragma unroll
    for (int e=0;e<16;e++) ent -= c[e]*logf(c[e]+1e-8f);
    sE[tid]=ent;
    #pragma unroll
    for (int e=0;e<16;e++) sC[tid][e]=c[e];
  }
  __syncthreads();
  if (tid<16){
    float ms=0.f, cs=0.f;
    #pragma unroll
    for (int tt=0;tt<32;tt++){ ms += sC[tt][tid]; cs += sN[tt][tid]; }
    musum_p[blk*16+tid]=ms; csum_p[blk*16+tid]=cs;
  }
  if (tid==16){
    float s=0.f;
    #pragma unroll
    for (int k=0;k<32;k++) s += sE[k];
    ent_p[blk]=s;
  }
  __syncthreads();
  // ---- P3: part6[blk][e][d] = sum_t sN[t][e]*x[t][d]; thread owns d4=tid ----
  {
    float4 acc[16];
    #pragma unroll
    for (int e=0;e<16;e++) acc[e]=make_float4(0,0,0,0);
    #pragma unroll 2
    for (int t=0;t<32;t++){
      const float4 xv = *(const float4*)(x + (size_t)(t0+t)*DIM + tid*4);
      #pragma unroll
      for (int qq=0;qq<4;qq++){
        float4 nq = *((const float4*)&sN[t][qq*4]);   // broadcast
        acc[qq*4+0].x=fmaf(nq.x,xv.x,acc[qq*4+0].x); acc[qq*4+0].y=fmaf(nq.x,xv.y,acc[qq*4+0].y);
        acc[qq*4+0].z=fmaf(nq.x,xv.z,acc[qq*4+0].z); acc[qq*4+0].w=fmaf(nq.x,xv.w,acc[qq*4+0].w);
        acc[qq*4+1].x=fmaf(nq.y,xv.x,acc[qq*4+1].x); acc[qq*4+1].y=fmaf(nq.y,xv.y,acc[qq*4+1].y);
        acc[qq*4+1].z=fmaf(nq.y,xv.z,acc[qq*4+1].z); acc[qq*4+1].w=fmaf(nq.y,xv.w,acc[qq*4+1].w);
        acc[qq*4+2].x=fmaf(nq.z,xv.x,acc[qq*4+2].x); acc[qq*4+2].y=fmaf(nq.z,xv.y,acc[qq*4+2].y);
        acc[qq*4+2].z=fmaf(nq.z,xv.z,acc[qq*4+2].z); acc[qq*4+2].w=fmaf(nq.z,xv.w,acc[qq*4+2].w);
        acc[qq*4+3].x=fmaf(nq.w,xv.x,acc[qq*4+3].x); acc[qq*4+3].y=fmaf(nq.w,xv.y,acc[qq*4+3].y);
        acc[qq*4+3].z=fmaf(nq.w,xv.z,acc[qq*4+3].z); acc[qq*4+3].w=fmaf(nq.w,xv.w,acc[qq*4+3].w);
      }
    }
    #pragma unroll
    for (int e=0;e<16;e++)
      *(float4*)(part6 + ((size_t)blk*16+e)*DIM + tid*4) = acc[e];
  }
}

// KE': sraw (inv_s folded) + dispatch (blk<512) + finalize (blk==1023). grid 1024 x 256
__global__ __launch_bounds__(256) void ke2(const float* __restrict__ part6,
    const float* __restrict__ csum_p, const float* __restrict__ num,
    const float* __restrict__ musum_p, const float* __restrict__ ent_p,
    const float* __restrict__ Wd,
    float* __restrict__ sraw, float* __restrict__ disp_out,
    float* __restrict__ loss_out, float* __restrict__ mu_out, float* __restrict__ ent_out){
  const int tid = threadIdx.x, blk = blockIdx.x;
  __shared__ float sIv[16][16];
  __shared__ float sInv[16];
  __shared__ float s2[256];
  { int g=tid>>4, e=tid&15;
    float v=0.f;
    #pragma unroll
    for (int k=0;k<16;k++) v += csum_p[(g*16+k)*16 + e];
    sIv[g][e]=v; }
  __syncthreads();
  if (tid<16){
    float v=0.f;
    #pragma unroll
    for (int g=0;g<16;g++) v += sIv[g][tid];
    sInv[tid]=1.f/v;
  }
  __syncthreads();
  // sraw: 32 outputs, 8-way tc split
  { const int ol=tid&31, sl=tid>>5;
    const int o = blk*32 + ol;
    float s=0.f;
    #pragma unroll 8
    for (int k=0;k<32;k++) s += part6[(size_t)(sl*32+k)*32768 + o];
    s2[tid]=s;
  }
  __syncthreads();
  if (tid<32){
    float t=0.f;
    #pragma unroll
    for (int k=0;k<8;k++) t += s2[k*32+tid];
    const int oo = blk*32 + tid;
    sraw[oo] = t * sInv[oo>>11];
  }
  if (blk<512){                                   // dispatch: 16 tokens/block
    const int t0 = blk*16;
    float v = num[(size_t)t0*16 + tid];           // 256 consecutive -> coalesced
    disp_out[(size_t)t0*16 + tid] = v * sInv[tid&15];
  }
  if (blk==1023){                                 // finalize loss/mu/ent
    __shared__ float sq[16][16];
    __shared__ float smu[16];
    __shared__ float sqv[16];
    __shared__ float sqe[16];
    { int s=tid>>4, ch=tid&15;
      const float* base = Wd + (size_t)s*DIM + ch*128;
      float qv=0.f;
      for (int ii=0;ii<128;ii+=4){ float4 v=*(const float4*)(base+ii); qv+=v.x+v.y+v.z+v.w; }
      sq[s][ch]=qv; }
    if (tid<16){
      float mu=0.f;
      for (int b=0;b<256;b++) mu += musum_p[b*16+tid];
      mu/=8192.f;
      mu_out[tid]=mu; smu[tid]=mu;
    }
    if (tid==32){ float es=0.f; for(int b=0;b<256;b++) es+=ent_p[b]; ent_out[0]=es/8192.f; }
    __syncthreads();
    if (tid<16){ float qv=0.f; for(int s=0;s<16;s++) qv+=sq[s][tid]; sqv[tid]=qv/2048.f; }
    __syncthreads();
    if (tid<16){
      float qm=-INFINITY;
      for (int e=0;e<16;e++) qm=fmaxf(qm,sqv[e]);
      sqe[tid]=expf(sqv[tid]-qm);
    }
    __syncthreads();
    if (tid==0){
      float qs=0.f; for(int e=0;e<16;e++) qs+=sqe[e];
      float loss=0.f; for(int e=0;e<16;e++) loss+=smu[e]*(sqe[e]/qs);
      loss_out[0]=16.f*loss;
    }
  }
}

// KF: h-GEMV (r3 structure, sraw pre-scaled). grid 512 = 16e x 32hc(32h)
__global__ __launch_bounds__(256) void kf_h(const float* __restrict__ sraw,
    const float* __restrict__ W1, const float* __restrict__ b1,
    float* __restrict__ hbuf){
  const int e  = blockIdx.x >> 5;
  const int hc = blockIdx.x & 31;
  const int hbase = hc*32;
  const int tid = threadIdx.x;
  __shared__ float sr[2048];
  __shared__ float sacc[256];
  { const float4* s4 = (const float4*)(sraw + (size_t)e*DIM);
    float4 a = s4[tid*2], b = s4[tid*2+1];
    *(float4*)(&sr[tid*8]) = a; *(float4*)(&sr[tid*8+4]) = b; }
  __syncthreads();
  const int hl = tid&31, ds = tid>>5;            // 8 d-slices, interleaved
  float acc = 0.f;
  const float* wp = W1 + (size_t)e*DIM*NH + hbase + hl;
  #pragma unroll 16
  for (int d2=0; d2<256; d2++){
    const int dd = d2*8 + ds;
    acc = fmaf(sr[dd], wp[(size_t)dd*NH], acc);
  }
  sacc[tid] = acc;
  __syncthreads();
  if (tid < 32){
    float s = 0.f;
    #pragma unroll
    for (int k=0;k<8;k++) s += sacc[k*32 + tid];
    float pre = s + b1[(size_t)e*NH + hbase + tid];
    hbuf[(size_t)e*NH + hbase + tid] = 0.5f*pre*(1.f+erff(pre*0.70710678118654752f));
  }
}

// KG: slot_out GEMV (r3 structure). grid 512 = 16e x 32dc(64d)
__global__ __launch_bounds__(256) void kg_so(const float* __restrict__ hbuf,
    const float* __restrict__ W2, const float* __restrict__ b2,
    float* __restrict__ slot_out){
  const int e  = blockIdx.x >> 5;
  const int dc = blockIdx.x & 31;
  const int dbase = dc*64;
  const int tid = threadIdx.x;
  __shared__ float hh[1024];
  __shared__ float sacc[256];
  { const float4* h4 = (const float4*)(hbuf + (size_t)e*NH);
    *(float4*)(&hh[tid*4]) = h4[tid]; }
  __syncthreads();
  const int dl = tid&63, hs = tid>>6;            // 4 h-slices, interleaved
  float acc = 0.f;
  const float* wp = W2 + (size_t)e*NH*DIM + dbase + dl;
  #pragma unroll 16
  for (int h2=0; h2<256; h2++){
    const int hidx = h2*4 + hs;
    acc = fmaf(hh[hidx], wp[(size_t)hidx*DIM], acc);
  }
  sacc[tid] = acc;
  __syncthreads();
  if (tid < 64){
    float s = sacc[tid] + sacc[64+tid] + sacc[128+tid] + sacc[192+tid];
    slot_out[(size_t)e*DIM + dbase + tid] = s + b2[(size_t)e*DIM + dbase + tid];
  }
}

// KH: out = combine @ slot_out. grid 1024 = 512tb(16tok) x 2dc
__global__ __launch_bounds__(256) void kh_out(const float* __restrict__ slot_out,
    const float* __restrict__ combine, float* __restrict__ out){
  const int tb = blockIdx.x >> 1;
  const int dc = blockIdx.x & 1;
  const int t0 = tb*16;
  const int d  = dc*1024 + threadIdx.x*4;
  float4 sv[16];
  #pragma unroll
  for (int e=0;e<16;e++) sv[e] = *(const float4*)(slot_out + (size_t)e*DIM + d);
  #pragma unroll 2
  for (int t=0;t<16;t++){
    const float* cr = combine + (size_t)(t0+t)*16;
    float4 a = make_float4(0,0,0,0);
    #pragma unroll
    for (int e=0;e<16;e++){
      float c = cr[e];
      a.x=fmaf(c,sv[e].x,a.x); a.y=fmaf(c,sv[e].y,a.y);
      a.z=fmaf(c,sv[e].z,a.z); a.w=fmaf(c,sv[e].w,a.w);
    }
    *(float4*)(out + (size_t)(t0+t)*DIM + d) = a;
  }
}

extern "C" void kernel_launch(void* const* d_in, const int* in_sizes, int n_in,
                              void* d_out, int out_size, void* d_ws, size_t ws_size,
                              hipStream_t stream) {
  const float* x  = (const float*)d_in[0];
  const float* Wd = (const float*)d_in[1];
  const float* W1 = (const float*)d_in[2];
  const float* b1 = (const float*)d_in[3];
  const float* W2 = (const float*)d_in[4];
  const float* b2 = (const float*)d_in[5];
  float* out = (float*)d_out;
  float* ws  = (float*)d_ws;

  float* part6 = ws + OFF_PART6;
  float* num   = ws + OFF_NUM;
  float* comb  = ws + OFF_COMB;
  float* csump = ws + OFF_CSUM;
  float* musump= ws + OFF_MUSUM;
  float* entp  = ws + OFF_ENT;
  float* sraw  = ws + OFF_SRAW;
  float* hbuf  = ws + OFF_HBUF;
  float* slot  = ws + OFF_SLOT;

  kad<<<256, 512, 0, stream>>>(x, Wd, num, comb, out + O_GATE, out + O_TOPI,
                               out + O_TOPW, csump, musump, entp, part6);
  ke2<<<1024, 256, 0, stream>>>(part6, csump, num, musump, entp, Wd,
                                sraw, out + O_DISP, out + O_LOSS,
                                out + O_MU, out + O_ENTR);
  kf_h<<<512, 256, 0, stream>>>(sraw, W1, b1, hbuf);
  kg_so<<<512, 256, 0, stream>>>(hbuf, W2, b2, slot);
  kh_out<<<1024, 256, 0, stream>>>(slot, comb, out + O_OUT);
}

// Round 10
// 204.517 us; speedup vs baseline: 1.0461x; 1.0461x over previous
//
#include <hip/hip_runtime.h>
#include <math.h>

#define TTOK 8192
#define DIM  2048
#define NH   1024

// ---- workspace layout (float offsets) ----
// part1 [8192][64][16] = 8388608 floats aliases part6 [256][16][2048] (= same size);
// part1 dead after KB, part6 written by KD (stream-ordered after KB). Total 35 MB.
#define OFF_ALIAS 0u
#define OFF_NUM   8388608u    // [8192][16]
#define OFF_COMB  8519680u    // [8192][16]
#define OFF_CSUM  8650752u    // [128][16]
#define OFF_MUSUM 8652800u    // [128][16]
#define OFF_ENT   8654848u    // [128]
#define OFF_SRAW  8654976u    // [16][2048]
#define OFF_HBUF  8687744u    // [16][1024]
#define OFF_SLOT  8704128u    // [16][2048] -> end 8736896 floats = 34.9 MB

// ---- d_out layout (float offsets) ----
#define O_OUT   0u
#define O_LOSS  16777216u
#define O_GATE  16777217u
#define O_TOPI  16908289u
#define O_TOPW  16924673u
#define O_MU    16941057u
#define O_ENTR  16941073u
#define O_DISP  16941074u

__device__ __forceinline__ float wave_sum(float v){
  #pragma unroll
  for (int o=1;o<64;o<<=1) v += __shfl_xor(v,o,64);
  return v;
}

// KA: logits partials, token-major part1[t][64kc][16].
// grid 1024 = 16tb(512tok) x 64kc(32 floats); 2 tokens/thread; Wd loads block-uniform.
__global__ __launch_bounds__(256,4) void ka_logits(const float* __restrict__ x,
                                                   const float* __restrict__ Wd,
                                                   float* __restrict__ part1){
  const int tb = blockIdx.x >> 6;
  const int kc = blockIdx.x & 63;                // block-uniform -> scalar Wd loads
  const int t0 = tb*512 + threadIdx.x;
  const int t1 = t0 + 256;
  const float4* __restrict__ xr0 = (const float4*)(x + (size_t)t0*DIM + kc*32);
  const float4* __restrict__ xr1 = (const float4*)(x + (size_t)t1*DIM + kc*32);
  float a0[16], a1[16];
  #pragma unroll
  for (int e=0;e<16;e++){ a0[e]=0.f; a1[e]=0.f; }
  #pragma unroll
  for (int k4=0;k4<8;k4++){
    float4 x0 = xr0[k4];
    float4 x1 = xr1[k4];
    #pragma unroll
    for (int e=0;e<16;e++){
      float4 w = *(const float4*)(Wd + e*DIM + kc*32 + k4*4);   // uniform
      a0[e] += x0.x*w.x + x0.y*w.y + x0.z*w.z + x0.w*w.w;
      a1[e] += x1.x*w.x + x1.y*w.y + x1.z*w.z + x1.w*w.w;
    }
  }
  float4* p0 = (float4*)(part1 + ((size_t)t0*64 + kc)*16);
  p0[0]=make_float4(a0[0],a0[1],a0[2],a0[3]);   p0[1]=make_float4(a0[4],a0[5],a0[6],a0[7]);
  p0[2]=make_float4(a0[8],a0[9],a0[10],a0[11]); p0[3]=make_float4(a0[12],a0[13],a0[14],a0[15]);
  float4* p1 = (float4*)(part1 + ((size_t)t1*64 + kc)*16);
  p1[0]=make_float4(a1[0],a1[1],a1[2],a1[3]);   p1[1]=make_float4(a1[4],a1[5],a1[6],a1[7]);
  p1[2]=make_float4(a1[8],a1[9],a1[10],a1[11]); p1[3]=make_float4(a1[12],a1[13],a1[14],a1[15]);
}

// KB: reduce part1 (4KB contiguous per token) -> num=exp(logits); csum partials;
// row softmax -> combine/gate/top2; musum/ent partials. grid 128 x 256 (64 tok/blk).
__global__ __launch_bounds__(256) void kb_router(const float* __restrict__ part1,
    float* __restrict__ num, float* __restrict__ csum_part,
    float* __restrict__ combine, float* __restrict__ gate_out,
    float* __restrict__ topi_out, float* __restrict__ topw_out,
    float* __restrict__ musum_part, float* __restrict__ ent_part){
  const int tid = threadIdx.x;
  const int i = blockIdx.x*256 + tid;            // (t,q): t=i>>2, q=i&3
  const float4* p1 = (const float4*)part1;       // token row = 256 float4
  const size_t base = (size_t)(i>>2)*256 + (i&3);
  float4 s = make_float4(0,0,0,0);
  #pragma unroll 8
  for (int kc=0;kc<64;kc++){
    float4 v = p1[base + kc*4];
    s.x+=v.x; s.y+=v.y; s.z+=v.z; s.w+=v.w;
  }
  float4 n4 = make_float4(expf(s.x),expf(s.y),expf(s.z),expf(s.w));
  ((float4*)num)[i] = n4;
  __shared__ float Lg[64][20];
  const int tl = tid>>2, q = tid&3;
  *(float4*)(&Lg[tl][q*4]) = s;
  float4 n = n4;
  #pragma unroll
  for (int o=4;o<64;o<<=1){
    n.x += __shfl_xor(n.x,o,64); n.y += __shfl_xor(n.y,o,64);
    n.z += __shfl_xor(n.z,o,64); n.w += __shfl_xor(n.w,o,64);
  }
  __shared__ float4 red[4][4];
  const int w = tid>>6, lane = tid&63;
  if (lane<4) red[w][lane] = n;
  __syncthreads();
  if (tid<4){
    float4 a=red[0][tid],b=red[1][tid],c=red[2][tid],d=red[3][tid];
    *(float4*)(csum_part + blockIdx.x*16 + tid*4) =
      make_float4(a.x+b.x+c.x+d.x, a.y+b.y+c.y+d.y, a.z+b.z+c.z+d.z, a.w+b.w+c.w+d.w);
  }
  if (tid < 64){
    const int gt = blockIdx.x*64 + tid;
    float l[16];
    #pragma unroll
    for (int e=0;e<16;e++) l[e] = Lg[tid][e];
    float m = l[0];
    #pragma unroll
    for (int e=1;e<16;e++) m = fmaxf(m,l[e]);
    float c[16]; float sm=0.f;
    #pragma unroll
    for (int e=0;e<16;e++){ c[e]=expf(l[e]-m); sm+=c[e]; }
    float inv = 1.f/sm;
    #pragma unroll
    for (int e=0;e<16;e++) c[e]*=inv;
    float4* co = (float4*)(combine + (size_t)gt*16);
    co[0]=make_float4(c[0],c[1],c[2],c[3]);   co[1]=make_float4(c[4],c[5],c[6],c[7]);
    co[2]=make_float4(c[8],c[9],c[10],c[11]); co[3]=make_float4(c[12],c[13],c[14],c[15]);
    float* go = gate_out + (size_t)gt*16;
    #pragma unroll
    for (int e=0;e<16;e++) go[e]=c[e];
    float v0=-1.f, v1=-1.f; int i0=0, i1=0;
    #pragma unroll
    for (int e=0;e<16;e++){
      float ce=c[e];
      if (ce>v0){ v1=v0; i1=i0; v0=ce; i0=e; }
      else if (ce>v1){ v1=ce; i1=e; }
    }
    float dn = fmaxf(v0+v1, 1e-8f);
    topi_out[(size_t)gt*2+0]=(float)i0; topi_out[(size_t)gt*2+1]=(float)i1;
    topw_out[(size_t)gt*2+0]=v0/dn;     topw_out[(size_t)gt*2+1]=v1/dn;
    float ent=0.f;
    #pragma unroll
    for (int e=0;e<16;e++) ent -= c[e]*logf(c[e]+1e-8f);
    #pragma unroll
    for (int e=0;e<16;e++){
      float v = wave_sum(c[e]);
      if (tid==0) musum_part[blockIdx.x*16+e] = v;
    }
    float ve = wave_sum(ent);
    if (tid==0) ent_part[blockIdx.x] = ve;
  }
}

// KD: pure slot_in partials. grid 512 = 256tc(32tok) x 2dc. part6 aliases part1.
__global__ __launch_bounds__(256) void kd_slotin(const float* __restrict__ x,
    const float* __restrict__ num, float* __restrict__ part6){
  const int tc = blockIdx.x >> 1;
  const int dc = blockIdx.x & 1;
  const int tid = threadIdx.x;
  const int d  = dc*1024 + tid*4;
  const int t0 = tc*32;
  __shared__ float4 sN[128];
  if (tid < 128) sN[tid] = ((const float4*)num)[t0*4 + tid];
  __syncthreads();
  float4 acc[16];
  #pragma unroll
  for (int e=0;e<16;e++) acc[e]=make_float4(0,0,0,0);
  #pragma unroll 2
  for (int t=0;t<32;t++){
    const float4 xv = *(const float4*)(x + (size_t)(t0+t)*DIM + d);
    #pragma unroll
    for (int qq=0;qq<4;qq++){
      float4 nq = sN[t*4+qq];
      acc[qq*4+0].x=fmaf(nq.x,xv.x,acc[qq*4+0].x); acc[qq*4+0].y=fmaf(nq.x,xv.y,acc[qq*4+0].y);
      acc[qq*4+0].z=fmaf(nq.x,xv.z,acc[qq*4+0].z); acc[qq*4+0].w=fmaf(nq.x,xv.w,acc[qq*4+0].w);
      acc[qq*4+1].x=fmaf(nq.y,xv.x,acc[qq*4+1].x); acc[qq*4+1].y=fmaf(nq.y,xv.y,acc[qq*4+1].y);
      acc[qq*4+1].z=fmaf(nq.y,xv.z,acc[qq*4+1].z); acc[qq*4+1].w=fmaf(nq.y,xv.w,acc[qq*4+1].w);
      acc[qq*4+2].x=fmaf(nq.z,xv.x,acc[qq*4+2].x); acc[qq*4+2].y=fmaf(nq.z,xv.y,acc[qq*4+2].y);
      acc[qq*4+2].z=fmaf(nq.z,xv.z,acc[qq*4+2].z); acc[qq*4+2].w=fmaf(nq.z,xv.w,acc[qq*4+2].w);
      acc[qq*4+3].x=fmaf(nq.w,xv.x,acc[qq*4+3].x); acc[qq*4+3].y=fmaf(nq.w,xv.y,acc[qq*4+3].y);
      acc[qq*4+3].z=fmaf(nq.w,xv.z,acc[qq*4+3].z); acc[qq*4+3].w=fmaf(nq.w,xv.w,acc[qq*4+3].w);
    }
  }
  #pragma unroll
  for (int e=0;e<16;e++)
    *(float4*)(part6 + ((size_t)tc*16+e)*DIM + d) = acc[e];
}

// KE2: sraw (inv_s folded) + dispatch (blk<512) + finalize (blk==1023). grid 1024 x 256
__global__ __launch_bounds__(256) void ke2(const float* __restrict__ part6,
    const float* __restrict__ csum_p, const float* __restrict__ num,
    const float* __restrict__ musum_p, const float* __restrict__ ent_p,
    const float* __restrict__ Wd,
    float* __restrict__ sraw, float* __restrict__ disp_out,
    float* __restrict__ loss_out, float* __restrict__ mu_out, float* __restrict__ ent_out){
  const int tid = threadIdx.x, blk = blockIdx.x;
  __shared__ float sIv[16][16];
  __shared__ float sInv[16];
  __shared__ float s2[256];
  { int g=tid>>4, e=tid&15;                     // 16 groups x 8 of 128 csum blocks
    float v=0.f;
    #pragma unroll
    for (int k=0;k<8;k++) v += csum_p[(g*8+k)*16 + e];
    sIv[g][e]=v; }
  __syncthreads();
  if (tid<16){
    float v=0.f;
    #pragma unroll
    for (int g=0;g<16;g++) v += sIv[g][tid];
    sInv[tid]=1.f/v;
  }
  __syncthreads();
  { const int ol=tid&31, sl=tid>>5;             // 8-way tc split
    const int o = blk*32 + ol;
    float s=0.f;
    #pragma unroll 8
    for (int k=0;k<32;k++) s += part6[(size_t)(sl*32+k)*32768 + o];
    s2[tid]=s;
  }
  __syncthreads();
  if (tid<32){
    float t=0.f;
    #pragma unroll
    for (int k=0;k<8;k++) t += s2[k*32+tid];
    const int oo = blk*32 + tid;
    sraw[oo] = t * sInv[oo>>11];
  }
  if (blk<512){                                  // dispatch: 16 tokens/block
    const int t0 = blk*16;
    float v = num[(size_t)t0*16 + tid];
    disp_out[(size_t)t0*16 + tid] = v * sInv[tid&15];
  }
  if (blk==1023){                                // finalize loss/mu/ent
    __shared__ float sq[16][16];
    __shared__ float smu[16];
    __shared__ float sqv[16];
    __shared__ float sqe[16];
    { int s=tid>>4, ch=tid&15;
      const float* base = Wd + (size_t)s*DIM + ch*128;
      float qv=0.f;
      for (int ii=0;ii<128;ii+=4){ float4 v=*(const float4*)(base+ii); qv+=v.x+v.y+v.z+v.w; }
      sq[s][ch]=qv; }
    if (tid<16){
      float mu=0.f;
      for (int b=0;b<128;b++) mu += musum_p[b*16+tid];
      mu/=8192.f;
      mu_out[tid]=mu; smu[tid]=mu;
    }
    if (tid==32){ float es=0.f; for(int b=0;b<128;b++) es+=ent_p[b]; ent_out[0]=es/8192.f; }
    __syncthreads();
    if (tid<16){ float qv=0.f; for(int s=0;s<16;s++) qv+=sq[s][tid]; sqv[tid]=qv/2048.f; }
    __syncthreads();
    if (tid<16){
      float qm=-INFINITY;
      for (int e=0;e<16;e++) qm=fmaxf(qm,sqv[e]);
      sqe[tid]=expf(sqv[tid]-qm);
    }
    __syncthreads();
    if (tid==0){
      float qs=0.f; for(int e=0;e<16;e++) qs+=sqe[e];
      float loss=0.f; for(int e=0;e<16;e++) loss+=smu[e]*(sqe[e]/qs);
      loss_out[0]=16.f*loss;
    }
  }
}

// KF: h-GEMV (r3 proven form; sraw pre-scaled). grid 512 = 16e x 32hc(32h)
__global__ __launch_bounds__(256) void kf_h(const float* __restrict__ sraw,
    const float* __restrict__ W1, const float* __restrict__ b1,
    float* __restrict__ hbuf){
  const int e  = blockIdx.x >> 5;
  const int hc = blockIdx.x & 31;
  const int hbase = hc*32;
  const int tid = threadIdx.x;
  __shared__ float sr[2048];
  __shared__ float sacc[256];
  { const float4* s4 = (const float4*)(sraw + (size_t)e*DIM);
    float4 a = s4[tid*2], b = s4[tid*2+1];
    *(float4*)(&sr[tid*8]) = a; *(float4*)(&sr[tid*8+4]) = b; }
  __syncthreads();
  const int hl = tid&31, ds = tid>>5;
  float acc = 0.f;
  const float* wp = W1 + (size_t)e*DIM*NH + hbase + hl;
  #pragma unroll 16
  for (int d2=0; d2<256; d2++){
    const int dd = d2*8 + ds;
    acc = fmaf(sr[dd], wp[(size_t)dd*NH], acc);
  }
  sacc[tid] = acc;
  __syncthreads();
  if (tid < 32){
    float s = 0.f;
    #pragma unroll
    for (int k=0;k<8;k++) s += sacc[k*32 + tid];
    float pre = s + b1[(size_t)e*NH + hbase + tid];
    hbuf[(size_t)e*NH + hbase + tid] = 0.5f*pre*(1.f+erff(pre*0.70710678118654752f));
  }
}

// KG: slot_out GEMV (r3 proven form). grid 512 = 16e x 32dc(64d)
__global__ __launch_bounds__(256) void kg_so(const float* __restrict__ hbuf,
    const float* __restrict__ W2, const float* __restrict__ b2,
    float* __restrict__ slot_out){
  const int e  = blockIdx.x >> 5;
  const int dc = blockIdx.x & 31;
  const int dbase = dc*64;
  const int tid = threadIdx.x;
  __shared__ float hh[1024];
  __shared__ float sacc[256];
  { const float4* h4 = (const float4*)(hbuf + (size_t)e*NH);
    *(float4*)(&hh[tid*4]) = h4[tid]; }
  __syncthreads();
  const int dl = tid&63, hs = tid>>6;
  float acc = 0.f;
  const float* wp = W2 + (size_t)e*NH*DIM + dbase + dl;
  #pragma unroll 16
  for (int h2=0; h2<256; h2++){
    const int hidx = h2*4 + hs;
    acc = fmaf(hh[hidx], wp[(size_t)hidx*DIM], acc);
  }
  sacc[tid] = acc;
  __syncthreads();
  if (tid < 64){
    float s = sacc[tid] + sacc[64+tid] + sacc[128+tid] + sacc[192+tid];
    slot_out[(size_t)e*DIM + dbase + tid] = s + b2[(size_t)e*DIM + dbase + tid];
  }
}

// KH: out = combine @ slot_out. grid 1024 = 512tb(16tok) x 2dc
__global__ __launch_bounds__(256) void kh_out(const float* __restrict__ slot_out,
    const float* __restrict__ combine, float* __restrict__ out){
  const int tb = blockIdx.x >> 1;
  const int dc = blockIdx.x & 1;
  const int t0 = tb*16;
  const int d  = dc*1024 + threadIdx.x*4;
  float4 sv[16];
  #pragma unroll
  for (int e=0;e<16;e++) sv[e] = *(const float4*)(slot_out + (size_t)e*DIM + d);
  #pragma unroll 2
  for (int t=0;t<16;t++){
    const float* cr = combine + (size_t)(t0+t)*16;
    float4 a = make_float4(0,0,0,0);
    #pragma unroll
    for (int e=0;e<16;e++){
      float c = cr[e];
      a.x=fmaf(c,sv[e].x,a.x); a.y=fmaf(c,sv[e].y,a.y);
      a.z=fmaf(c,sv[e].z,a.z); a.w=fmaf(c,sv[e].w,a.w);
    }
    *(float4*)(out + (size_t)(t0+t)*DIM + d) = a;
  }
}

extern "C" void kernel_launch(void* const* d_in, const int* in_sizes, int n_in,
                              void* d_out, int out_size, void* d_ws, size_t ws_size,
                              hipStream_t stream) {
  const float* x  = (const float*)d_in[0];
  const float* Wd = (const float*)d_in[1];
  const float* W1 = (const float*)d_in[2];
  const float* b1 = (const float*)d_in[3];
  const float* W2 = (const float*)d_in[4];
  const float* b2 = (const float*)d_in[5];
  float* out = (float*)d_out;
  float* ws  = (float*)d_ws;

  float* part1 = ws + OFF_ALIAS;   // [8192][64][16]
  float* part6 = ws + OFF_ALIAS;   // [256][16][2048], after part1 dead
  float* num   = ws + OFF_NUM;
  float* comb  = ws + OFF_COMB;
  float* csump = ws + OFF_CSUM;
  float* musump= ws + OFF_MUSUM;
  float* entp  = ws + OFF_ENT;
  float* sraw  = ws + OFF_SRAW;
  float* hbuf  = ws + OFF_HBUF;
  float* slot  = ws + OFF_SLOT;

  ka_logits<<<1024, 256, 0, stream>>>(x, Wd, part1);
  kb_router<<<128, 256, 0, stream>>>(part1, num, csump, comb, out + O_GATE,
                                     out + O_TOPI, out + O_TOPW, musump, entp);
  kd_slotin<<<512, 256, 0, stream>>>(x, num, part6);
  ke2<<<1024, 256, 0, stream>>>(part6, csump, num, musump, entp, Wd,
                                sraw, out + O_DISP, out + O_LOSS,
                                out + O_MU, out + O_ENTR);
  kf_h<<<512, 256, 0, stream>>>(sraw, W1, b1, hbuf);
  kg_so<<<512, 256, 0, stream>>>(hbuf, W2, b2, slot);
  kh_out<<<1024, 256, 0, stream>>>(slot, comb, out + O_OUT);
}

// Round 11
// 179.979 us; speedup vs baseline: 1.1887x; 1.1363x over previous
//
#include <hip/hip_runtime.h>
#include <math.h>

#define TTOK 8192
#define DIM  2048
#define NH   1024

// ---- workspace layout (float offsets) ----
// part1 [32][8192][16] = 4.2M floats lives inside the 8.4M-float alias region
// reused by part6 [256][16][2048] (part1 dead after KB). Total 34.9 MB (proven safe).
#define OFF_ALIAS 0u
#define OFF_NUM   8388608u    // [8192][16]
#define OFF_COMB  8519680u    // [8192][16]
#define OFF_CSUM  8650752u    // [128][16]
#define OFF_MUSUM 8652800u    // [128][16]
#define OFF_ENT   8654848u    // [128]
#define OFF_SRAW  8654976u    // [16][2048]
#define OFF_HBUF  8687744u    // [16][1024]
#define OFF_SLOT  8704128u    // [16][2048] -> end 8736896 floats = 34.9 MB

// ---- d_out layout (float offsets) ----
#define O_OUT   0u
#define O_LOSS  16777216u
#define O_GATE  16777217u
#define O_TOPI  16908289u
#define O_TOPW  16924673u
#define O_MU    16941057u
#define O_ENTR  16941073u
#define O_DISP  16941074u

__device__ __forceinline__ float wave_sum(float v){
  #pragma unroll
  for (int o=1;o<64;o<<=1) v += __shfl_xor(v,o,64);
  return v;
}

// KA: logits partials, kc-major part1[32kc][8192][16] (coalesced 4KB/wave stores).
// grid 1024 = 32tb(256tok) x 32kc(64 floats); 16 waves/CU; Wd loads block-uniform.
__global__ __launch_bounds__(256,4) void ka_logits(const float* __restrict__ x,
                                                   const float* __restrict__ Wd,
                                                   float* __restrict__ part1){
  const int tb = blockIdx.x >> 5;
  const int kc = blockIdx.x & 31;                // block-uniform -> scalar Wd loads
  const int t  = tb*256 + threadIdx.x;
  const float4* __restrict__ xr = (const float4*)(x + (size_t)t*DIM + kc*64);
  float acc[16];
  #pragma unroll
  for (int e=0;e<16;e++) acc[e]=0.f;
  #pragma unroll
  for (int k4=0;k4<16;k4++){
    float4 xv = xr[k4];
    #pragma unroll
    for (int e=0;e<16;e++){
      float4 w = *(const float4*)(Wd + e*DIM + kc*64 + k4*4);   // uniform
      acc[e] += xv.x*w.x + xv.y*w.y + xv.z*w.z + xv.w*w.w;
    }
  }
  float4* po = (float4*)(part1 + ((size_t)kc*TTOK + t)*16);
  po[0]=make_float4(acc[0],acc[1],acc[2],acc[3]);
  po[1]=make_float4(acc[4],acc[5],acc[6],acc[7]);
  po[2]=make_float4(acc[8],acc[9],acc[10],acc[11]);
  po[3]=make_float4(acc[12],acc[13],acc[14],acc[15]);
}

// KB: reduce part1 slice-major (1KB/instruction streams) -> num=exp(logits);
// csum partials; row softmax -> combine/gate/top2; musum/ent partials. grid 128 x 256.
__global__ __launch_bounds__(256) void kb_router(const float* __restrict__ part1,
    float* __restrict__ num, float* __restrict__ csum_part,
    float* __restrict__ combine, float* __restrict__ gate_out,
    float* __restrict__ topi_out, float* __restrict__ topw_out,
    float* __restrict__ musum_part, float* __restrict__ ent_part){
  const int tid = threadIdx.x;
  const int i = blockIdx.x*256 + tid;            // float4 idx over [8192][16]/4
  const float4* p1 = (const float4*)part1;
  float4 s = make_float4(0,0,0,0);
  #pragma unroll 8
  for (int kc=0;kc<32;kc++){
    float4 v = p1[(size_t)kc*32768 + i];         // lane-consecutive -> coalesced
    s.x+=v.x; s.y+=v.y; s.z+=v.z; s.w+=v.w;
  }
  float4 n4 = make_float4(expf(s.x),expf(s.y),expf(s.z),expf(s.w));
  ((float4*)num)[i] = n4;
  __shared__ float Lg[64][20];
  const int tl = tid>>2, q = tid&3;
  *(float4*)(&Lg[tl][q*4]) = s;
  float4 n = n4;
  #pragma unroll
  for (int o=4;o<64;o<<=1){
    n.x += __shfl_xor(n.x,o,64); n.y += __shfl_xor(n.y,o,64);
    n.z += __shfl_xor(n.z,o,64); n.w += __shfl_xor(n.w,o,64);
  }
  __shared__ float4 red[4][4];
  const int w = tid>>6, lane = tid&63;
  if (lane<4) red[w][lane] = n;
  __syncthreads();
  if (tid<4){
    float4 a=red[0][tid],b=red[1][tid],c=red[2][tid],d=red[3][tid];
    *(float4*)(csum_part + blockIdx.x*16 + tid*4) =
      make_float4(a.x+b.x+c.x+d.x, a.y+b.y+c.y+d.y, a.z+b.z+c.z+d.z, a.w+b.w+c.w+d.w);
  }
  if (tid < 64){
    const int gt = blockIdx.x*64 + tid;
    float l[16];
    #pragma unroll
    for (int e=0;e<16;e++) l[e] = Lg[tid][e];
    float m = l[0];
    #pragma unroll
    for (int e=1;e<16;e++) m = fmaxf(m,l[e]);
    float c[16]; float sm=0.f;
    #pragma unroll
    for (int e=0;e<16;e++){ c[e]=expf(l[e]-m); sm+=c[e]; }
    float inv = 1.f/sm;
    #pragma unroll
    for (int e=0;e<16;e++) c[e]*=inv;
    float4* co = (float4*)(combine + (size_t)gt*16);
    co[0]=make_float4(c[0],c[1],c[2],c[3]);   co[1]=make_float4(c[4],c[5],c[6],c[7]);
    co[2]=make_float4(c[8],c[9],c[10],c[11]); co[3]=make_float4(c[12],c[13],c[14],c[15]);
    float* go = gate_out + (size_t)gt*16;
    #pragma unroll
    for (int e=0;e<16;e++) go[e]=c[e];
    float v0=-1.f, v1=-1.f; int i0=0, i1=0;
    #pragma unroll
    for (int e=0;e<16;e++){
      float ce=c[e];
      if (ce>v0){ v1=v0; i1=i0; v0=ce; i0=e; }
      else if (ce>v1){ v1=ce; i1=e; }
    }
    float dn = fmaxf(v0+v1, 1e-8f);
    topi_out[(size_t)gt*2+0]=(float)i0; topi_out[(size_t)gt*2+1]=(float)i1;
    topw_out[(size_t)gt*2+0]=v0/dn;     topw_out[(size_t)gt*2+1]=v1/dn;
    float ent=0.f;
    #pragma unroll
    for (int e=0;e<16;e++) ent -= c[e]*logf(c[e]+1e-8f);
    #pragma unroll
    for (int e=0;e<16;e++){
      float v = wave_sum(c[e]);
      if (tid==0) musum_part[blockIdx.x*16+e] = v;
    }
    float ve = wave_sum(ent);
    if (tid==0) ent_part[blockIdx.x] = ve;
  }
}

// KD: pure slot_in partials. grid 512 = 256tc(32tok) x 2dc. part6 aliases part1.
__global__ __launch_bounds__(256) void kd_slotin(const float* __restrict__ x,
    const float* __restrict__ num, float* __restrict__ part6){
  const int tc = blockIdx.x >> 1;
  const int dc = blockIdx.x & 1;
  const int tid = threadIdx.x;
  const int d  = dc*1024 + tid*4;
  const int t0 = tc*32;
  __shared__ float4 sN[128];
  if (tid < 128) sN[tid] = ((const float4*)num)[t0*4 + tid];
  __syncthreads();
  float4 acc[16];
  #pragma unroll
  for (int e=0;e<16;e++) acc[e]=make_float4(0,0,0,0);
  #pragma unroll 2
  for (int t=0;t<32;t++){
    const float4 xv = *(const float4*)(x + (size_t)(t0+t)*DIM + d);
    #pragma unroll
    for (int qq=0;qq<4;qq++){
      float4 nq = sN[t*4+qq];
      acc[qq*4+0].x=fmaf(nq.x,xv.x,acc[qq*4+0].x); acc[qq*4+0].y=fmaf(nq.x,xv.y,acc[qq*4+0].y);
      acc[qq*4+0].z=fmaf(nq.x,xv.z,acc[qq*4+0].z); acc[qq*4+0].w=fmaf(nq.x,xv.w,acc[qq*4+0].w);
      acc[qq*4+1].x=fmaf(nq.y,xv.x,acc[qq*4+1].x); acc[qq*4+1].y=fmaf(nq.y,xv.y,acc[qq*4+1].y);
      acc[qq*4+1].z=fmaf(nq.y,xv.z,acc[qq*4+1].z); acc[qq*4+1].w=fmaf(nq.y,xv.w,acc[qq*4+1].w);
      acc[qq*4+2].x=fmaf(nq.z,xv.x,acc[qq*4+2].x); acc[qq*4+2].y=fmaf(nq.z,xv.y,acc[qq*4+2].y);
      acc[qq*4+2].z=fmaf(nq.z,xv.z,acc[qq*4+2].z); acc[qq*4+2].w=fmaf(nq.z,xv.w,acc[qq*4+2].w);
      acc[qq*4+3].x=fmaf(nq.w,xv.x,acc[qq*4+3].x); acc[qq*4+3].y=fmaf(nq.w,xv.y,acc[qq*4+3].y);
      acc[qq*4+3].z=fmaf(nq.w,xv.z,acc[qq*4+3].z); acc[qq*4+3].w=fmaf(nq.w,xv.w,acc[qq*4+3].w);
    }
  }
  #pragma unroll
  for (int e=0;e<16;e++)
    *(float4*)(part6 + ((size_t)tc*16+e)*DIM + d) = acc[e];
}

// KE2: sraw (inv_s folded) + dispatch (blk<512) + finalize (blk==1023). grid 1024 x 256
__global__ __launch_bounds__(256) void ke2(const float* __restrict__ part6,
    const float* __restrict__ csum_p, const float* __restrict__ num,
    const float* __restrict__ musum_p, const float* __restrict__ ent_p,
    const float* __restrict__ Wd,
    float* __restrict__ sraw, float* __restrict__ disp_out,
    float* __restrict__ loss_out, float* __restrict__ mu_out, float* __restrict__ ent_out){
  const int tid = threadIdx.x, blk = blockIdx.x;
  __shared__ float sIv[16][16];
  __shared__ float sInv[16];
  __shared__ float s2[256];
  { int g=tid>>4, e=tid&15;                     // 16 groups x 8 of 128 csum blocks
    float v=0.f;
    #pragma unroll
    for (int k=0;k<8;k++) v += csum_p[(g*8+k)*16 + e];
    sIv[g][e]=v; }
  __syncthreads();
  if (tid<16){
    float v=0.f;
    #pragma unroll
    for (int g=0;g<16;g++) v += sIv[g][tid];
    sInv[tid]=1.f/v;
  }
  __syncthreads();
  { const int ol=tid&31, sl=tid>>5;             // 8-way tc split
    const int o = blk*32 + ol;
    float s=0.f;
    #pragma unroll 8
    for (int k=0;k<32;k++) s += part6[(size_t)(sl*32+k)*32768 + o];
    s2[tid]=s;
  }
  __syncthreads();
  if (tid<32){
    float t=0.f;
    #pragma unroll
    for (int k=0;k<8;k++) t += s2[k*32+tid];
    const int oo = blk*32 + tid;
    sraw[oo] = t * sInv[oo>>11];
  }
  if (blk<512){                                  // dispatch: 16 tokens/block
    const int t0 = blk*16;
    float v = num[(size_t)t0*16 + tid];
    disp_out[(size_t)t0*16 + tid] = v * sInv[tid&15];
  }
  if (blk==1023){                                // finalize loss/mu/ent
    __shared__ float sq[16][16];
    __shared__ float smu[16];
    __shared__ float sqv[16];
    __shared__ float sqe[16];
    { int s=tid>>4, ch=tid&15;
      const float* base = Wd + (size_t)s*DIM + ch*128;
      float qv=0.f;
      for (int ii=0;ii<128;ii+=4){ float4 v=*(const float4*)(base+ii); qv+=v.x+v.y+v.z+v.w; }
      sq[s][ch]=qv; }
    if (tid<16){
      float mu=0.f;
      for (int b=0;b<128;b++) mu += musum_p[b*16+tid];
      mu/=8192.f;
      mu_out[tid]=mu; smu[tid]=mu;
    }
    if (tid==32){ float es=0.f; for(int b=0;b<128;b++) es+=ent_p[b]; ent_out[0]=es/8192.f; }
    __syncthreads();
    if (tid<16){ float qv=0.f; for(int s=0;s<16;s++) qv+=sq[s][tid]; sqv[tid]=qv/2048.f; }
    __syncthreads();
    if (tid<16){
      float qm=-INFINITY;
      for (int e=0;e<16;e++) qm=fmaxf(qm,sqv[e]);
      sqe[tid]=expf(sqv[tid]-qm);
    }
    __syncthreads();
    if (tid==0){
      float qs=0.f; for(int e=0;e<16;e++) qs+=sqe[e];
      float loss=0.f; for(int e=0;e<16;e++) loss+=smu[e]*(sqe[e]/qs);
      loss_out[0]=16.f*loss;
    }
  }
}

// KF: h-GEMV (r3 proven form; sraw pre-scaled). grid 512 = 16e x 32hc(32h)
__global__ __launch_bounds__(256) void kf_h(const float* __restrict__ sraw,
    const float* __restrict__ W1, const float* __restrict__ b1,
    float* __restrict__ hbuf){
  const int e  = blockIdx.x >> 5;
  const int hc = blockIdx.x & 31;
  const int hbase = hc*32;
  const int tid = threadIdx.x;
  __shared__ float sr[2048];
  __shared__ float sacc[256];
  { const float4* s4 = (const float4*)(sraw + (size_t)e*DIM);
    float4 a = s4[tid*2], b = s4[tid*2+1];
    *(float4*)(&sr[tid*8]) = a; *(float4*)(&sr[tid*8+4]) = b; }
  __syncthreads();
  const int hl = tid&31, ds = tid>>5;
  float acc = 0.f;
  const float* wp = W1 + (size_t)e*DIM*NH + hbase + hl;
  #pragma unroll 16
  for (int d2=0; d2<256; d2++){
    const int dd = d2*8 + ds;
    acc = fmaf(sr[dd], wp[(size_t)dd*NH], acc);
  }
  sacc[tid] = acc;
  __syncthreads();
  if (tid < 32){
    float s = 0.f;
    #pragma unroll
    for (int k=0;k<8;k++) s += sacc[k*32 + tid];
    float pre = s + b1[(size_t)e*NH + hbase + tid];
    hbuf[(size_t)e*NH + hbase + tid] = 0.5f*pre*(1.f+erff(pre*0.70710678118654752f));
  }
}

// KG: slot_out GEMV (r3 proven form). grid 512 = 16e x 32dc(64d)
__global__ __launch_bounds__(256) void kg_so(const float* __restrict__ hbuf,
    const float* __restrict__ W2, const float* __restrict__ b2,
    float* __restrict__ slot_out){
  const int e  = blockIdx.x >> 5;
  const int dc = blockIdx.x & 31;
  const int dbase = dc*64;
  const int tid = threadIdx.x;
  __shared__ float hh[1024];
  __shared__ float sacc[256];
  { const float4* h4 = (const float4*)(hbuf + (size_t)e*NH);
    *(float4*)(&hh[tid*4]) = h4[tid]; }
  __syncthreads();
  const int dl = tid&63, hs = tid>>6;
  float acc = 0.f;
  const float* wp = W2 + (size_t)e*NH*DIM + dbase + dl;
  #pragma unroll 16
  for (int h2=0; h2<256; h2++){
    const int hidx = h2*4 + hs;
    acc = fmaf(hh[hidx], wp[(size_t)hidx*DIM], acc);
  }
  sacc[tid] = acc;
  __syncthreads();
  if (tid < 64){
    float s = sacc[tid] + sacc[64+tid] + sacc[128+tid] + sacc[192+tid];
    slot_out[(size_t)e*DIM + dbase + tid] = s + b2[(size_t)e*DIM + dbase + tid];
  }
}

// KH: out = combine @ slot_out. grid 1024 = 512tb(16tok) x 2dc
__global__ __launch_bounds__(256) void kh_out(const float* __restrict__ slot_out,
    const float* __restrict__ combine, float* __restrict__ out){
  const int tb = blockIdx.x >> 1;
  const int dc = blockIdx.x & 1;
  const int t0 = tb*16;
  const int d  = dc*1024 + threadIdx.x*4;
  float4 sv[16];
  #pragma unroll
  for (int e=0;e<16;e++) sv[e] = *(const float4*)(slot_out + (size_t)e*DIM + d);
  #pragma unroll 2
  for (int t=0;t<16;t++){
    const float* cr = combine + (size_t)(t0+t)*16;
    float4 a = make_float4(0,0,0,0);
    #pragma unroll
    for (int e=0;e<16;e++){
      float c = cr[e];
      a.x=fmaf(c,sv[e].x,a.x); a.y=fmaf(c,sv[e].y,a.y);
      a.z=fmaf(c,sv[e].z,a.z); a.w=fmaf(c,sv[e].w,a.w);
    }
    *(float4*)(out + (size_t)(t0+t)*DIM + d) = a;
  }
}

extern "C" void kernel_launch(void* const* d_in, const int* in_sizes, int n_in,
                              void* d_out, int out_size, void* d_ws, size_t ws_size,
                              hipStream_t stream) {
  const float* x  = (const float*)d_in[0];
  const float* Wd = (const float*)d_in[1];
  const float* W1 = (const float*)d_in[2];
  const float* b1 = (const float*)d_in[3];
  const float* W2 = (const float*)d_in[4];
  const float* b2 = (const float*)d_in[5];
  float* out = (float*)d_out;
  float* ws  = (float*)d_ws;

  float* part1 = ws + OFF_ALIAS;   // [32][8192][16]
  float* part6 = ws + OFF_ALIAS;   // [256][16][2048], after part1 dead
  float* num   = ws + OFF_NUM;
  float* comb  = ws + OFF_COMB;
  float* csump = ws + OFF_CSUM;
  float* musump= ws + OFF_MUSUM;
  float* entp  = ws + OFF_ENT;
  float* sraw  = ws + OFF_SRAW;
  float* hbuf  = ws + OFF_HBUF;
  float* slot  = ws + OFF_SLOT;

  ka_logits<<<1024, 256, 0, stream>>>(x, Wd, part1);
  kb_router<<<128, 256, 0, stream>>>(part1, num, csump, comb, out + O_GATE,
                                     out + O_TOPI, out + O_TOPW, musump, entp);
  kd_slotin<<<512, 256, 0, stream>>>(x, num, part6);
  ke2<<<1024, 256, 0, stream>>>(part6, csump, num, musump, entp, Wd,
                                sraw, out + O_DISP, out + O_LOSS,
                                out + O_MU, out + O_ENTR);
  kf_h<<<512, 256, 0, stream>>>(sraw, W1, b1, hbuf);
  kg_so<<<512, 256, 0, stream>>>(hbuf, W2, b2, slot);
  kh_out<<<1024, 256, 0, stream>>>(slot, comb, out + O_OUT);
}